// Round 4
// baseline (305.590 us; speedup 1.0000x reference)
//
#include <hip/hip_runtime.h>

#define HHH   28
#define NPIX  784
#define NSTRIP 7           // 28 rows / 4-row strips
#define M_PIX 112          // 4 rows * 28 = pixels per strip = 7 M-tiles of 16
#define KBAND 336          // 12 input rows cover all taps of a 4-row strip (|jitter|<=2)
#define NKT   11           // K padded to 352 = 11 tiles of 32
#define XPITCH 360         // f16 row pitch (+8 pad: 180-dword stride -> 2-way banks max, free)
#define NB    64           // batch tile (N) = 4 N-tiles of 16
#define NNT   4
#define BLOCK 448          // 7 waves; wave w owns M-tile w (A-frags live in its registers)
#define CHUNKS 74          // 7x74 = 518 blocks ~= 2/CU (LDS 46 KB -> 2 blocks/CU)

typedef _Float16 half8  __attribute__((ext_vector_type(8)));
typedef _Float16 half4h __attribute__((ext_vector_type(4)));
typedef float    floatx4 __attribute__((ext_vector_type(4)));

__global__ __launch_bounds__(BLOCK, 4) void axs_89807766159734_kernel(
    const float* __restrict__ x, const float* __restrict__ pos2d,
    const float* __restrict__ weight, float* __restrict__ out,
    int tilesPerChunk, int totalTiles)
{
    __shared__ _Float16 X16[NB * XPITCH];   // X[b][k] f16, 46,080 B
    __shared__ int s_rlo;

    const int strip = blockIdx.x;           // 0..6
    const int chunk = blockIdx.y;           // 0..73
    const int tid  = threadIdx.x;
    const int lane = tid & 63;
    const int w    = tid >> 6;              // wave id = M-tile
    const int ml   = lane & 15;             // A: m-in-tile | B: n (batch) | D: col
    const int g    = lane >> 4;             // quad

    // ---- per-lane pixel (for A-build) ----
    const int p_glob = strip * M_PIX + w * 16 + ml;      // < 784
    const float p0 = pos2d[2 * p_glob];
    const float p1 = pos2d[2 * p_glob + 1];
    const float sw = fmaxf(weight[p_glob], 0.f);         // relu(weight)
    const float ce0f = rintf(p0);                        // == jnp.round (half-even)
    const int ce0 = (int)ce0f, ce1 = (int)rintf(p1);

    // strip's band start row = min(ce0)-2 (dynamic: robust to one-sided jitter>2)
    if (tid == 0) s_rlo = 1 << 30;
    __syncthreads();
    if (lane < 16) atomicMin(&s_rlo, ce0 - 2);
    __syncthreads();
    const int r_lo = s_rlo;

    // ---- build A-fragments in registers: af[Kt][j] = A[p][k=Kt*32+g*8+j] ----
    // Slot-scan (derive (i0,i1) from slot): no aliasing, OOB taps never appear;
    // reference's clamp+mask == "tap contributes 0" == slot stays 0.  exp done ONCE.
    half8 af[NKT];
#pragma unroll
    for (int Kt = 0; Kt < NKT; ++Kt) {
#pragma unroll
        for (int j = 0; j < 8; ++j) {
            const int k = Kt * 32 + g * 8 + j;
            const int qr = (int)(((unsigned)k * 2341u) >> 16);   // k/28 for k<1400
            const int qc = k - 28 * qr;
            const int qrow = r_lo + qr;
            const int i0 = qrow - ce0, i1 = qc - ce1;
            float coef = 0.f;
            if (i0 >= -2 && i0 <= 2 && i1 >= -2 && i1 <= 2 &&
                qrow >= 0 && qrow < HHH && k < KBAND) {
                const float d0 = (float)qrow - p0, d1 = (float)qc - p1;
                coef = sw * __expf(-0.5f * (d0 * d0 + d1 * d1));
            }
            af[Kt][j] = (_Float16)coef;
        }
    }

    const int k_lo = max(0, -r_lo * 28);                 // global-bounds clip for staging
    const int k_hi = min(KBAND, (HHH - r_lo) * 28);
    const int tile0 = chunk * tilesPerChunk;

    for (int t = 0; t < tilesPerChunk; ++t) {
        const int tile = tile0 + t;
        if (tile >= totalTiles) break;
        const int bbase = tile * NB;

        __syncthreads();                                 // X16 free (prev compute done)
        // ---- stage X tile: 64 batches x 336 f32 (contiguous rows r_lo..r_lo+11) -> f16 ----
        for (int e = tid; e < NB * (XPITCH / 4); e += BLOCK) {
            const int b  = e / (XPITCH / 4);
            const int k0 = (e - b * (XPITCH / 4)) * 4;
            const float* src = x + (size_t)(bbase + b) * NPIX + r_lo * 28;
            half4h h;
#pragma unroll
            for (int j = 0; j < 4; ++j) {
                const int k = k0 + j;
                h[j] = (_Float16)((k >= k_lo && k < k_hi) ? src[k] : 0.f);
            }
            *(half4h*)&X16[b * XPITCH + k0] = h;         // 8B LDS writes, conflict-free
        }
        __syncthreads();

        // ---- MFMA: D[112 x 64] += A[112 x 352] * X^T, A from registers ----
        floatx4 acc[NNT];
#pragma unroll
        for (int Nt = 0; Nt < NNT; ++Nt) acc[Nt] = (floatx4){0.f, 0.f, 0.f, 0.f};
#pragma unroll
        for (int Kt = 0; Kt < NKT; ++Kt) {
#pragma unroll
            for (int Nt = 0; Nt < NNT; ++Nt) {
                const half8 bf = *(const half8*)&X16[(Nt * 16 + ml) * XPITCH + Kt * 32 + g * 8];
                acc[Nt] = __builtin_amdgcn_mfma_f32_16x16x32_f16(af[Kt], bf, acc[Nt], 0, 0, 0);
            }
        }

        // ---- store: D col=ml=batch, row=g*4+reg=pixel -> float4 per lane, full 64B lines ----
        const int pg = strip * M_PIX + w * 16 + g * 4;
#pragma unroll
        for (int Nt = 0; Nt < NNT; ++Nt) {
            const int bg = bbase + Nt * 16 + ml;
            *(floatx4*)&out[(size_t)bg * NPIX + pg] = acc[Nt];
        }
    }
}

extern "C" void kernel_launch(void* const* d_in, const int* in_sizes, int n_in,
                              void* d_out, int out_size, void* d_ws, size_t ws_size,
                              hipStream_t stream) {
    const float* x      = (const float*)d_in[0];   // (32768,1,28,28) fp32
    const float* pos2d  = (const float*)d_in[1];   // (28,28,2) fp32
    const float* weight = (const float*)d_in[2];   // (28,28) fp32
    float* out = (float*)d_out;

    const int B = in_sizes[0] / NPIX;              // 32768
    const int totalTiles = B / NB;                 // 512 batch-tiles (per strip)
    const int tilesPerChunk = (totalTiles + CHUNKS - 1) / CHUNKS;   // 7

    // blockIdx linear = strip + 7*chunk: all 7 strips of a batch-chunk co-resident
    // -> the 3x band-overlap re-reads hit LLC (206 MB working set < 256 MB).
    hipLaunchKernelGGL(axs_89807766159734_kernel, dim3(NSTRIP, CHUNKS), dim3(BLOCK), 0, stream,
                       x, pos2d, weight, out, tilesPerChunk, totalTiles);
}

// Round 5
// 304.825 us; speedup vs baseline: 1.0025x; 1.0025x over previous
//
#include <hip/hip_runtime.h>

#define HHH   28
#define NPIX  784
#define NSTRIP 7           // 28 rows / 4-row strips
#define M_PIX 112          // pixels per strip = 7 M-tiles of 16
#define BROWS 14           // band rows (in-bounds by construction, r_lo in [0,14] even)
#define KBAND 392          // 14*28 real ks
#define NKT   13           // K tiled to 416 (ks 392..415 are zero pad)
#define XPITCH 424         // f16 pitch: 212-dword lane stride -> 2-way banks (free); 16B-align ok
#define NB    64           // batch tile = 4 N-tiles of 16
#define NNT   4
#define BLOCK 448          // 7 waves; wave w owns M-tile w, A-frags in registers
#define CHUNKS 74          // 7x74 = 518 blocks ~= 2/CU (LDS 54 KB -> 2 blocks/CU)

typedef _Float16 half8  __attribute__((ext_vector_type(8)));
typedef _Float16 half4h __attribute__((ext_vector_type(4)));
typedef float    floatx4 __attribute__((ext_vector_type(4)));

__global__ __launch_bounds__(BLOCK, 4) void axs_89807766159734_kernel(
    const float* __restrict__ x, const float* __restrict__ pos2d,
    const float* __restrict__ weight, float* __restrict__ out,
    int tilesPerChunk, int totalTiles)
{
    __shared__ _Float16 X16[NB * XPITCH];   // 54,272 B
    __shared__ int s_rlo;

    const int strip = blockIdx.x;           // 0..6
    const int chunk = blockIdx.y;           // 0..CHUNKS-1
    const int tid  = threadIdx.x;
    const int lane = tid & 63;
    const int w    = tid >> 6;              // wave id = M-tile
    const int ml   = lane & 15;             // A: m | B: n | D: col(batch)
    const int g    = lane >> 4;             // quad

    // ---- per-lane pixel ----
    const int p_glob = strip * M_PIX + w * 16 + ml;
    const float p0 = pos2d[2 * p_glob];
    const float p1 = pos2d[2 * p_glob + 1];
    const float sw = fmaxf(weight[p_glob], 0.f);         // relu(weight)
    const int ce0 = (int)rintf(p0), ce1 = (int)rintf(p1); // == jnp.round

    // band start: even, clamped so rows [r_lo, r_lo+13] are ALWAYS in-bounds
    if (tid == 0) s_rlo = 1 << 30;
    __syncthreads();
    if (lane < 16) atomicMin(&s_rlo, (ce0 - 2) & ~1);
    __syncthreads();
    const int r_lo = min(max(s_rlo, 0), HHH - BROWS);    // in [0,14], even

    // ---- A-fragments in registers: af[Kt][j] = A[p][k=Kt*32+g*8+j] (exp done once/chunk) ----
    half8 af[NKT];
#pragma unroll
    for (int Kt = 0; Kt < NKT; ++Kt) {
#pragma unroll
        for (int j = 0; j < 8; ++j) {
            const int k = Kt * 32 + g * 8 + j;
            const int qr = (int)(((unsigned)k * 2341u) >> 16);   // k/28 (k<1400)
            const int qc = k - 28 * qr;
            const int qrow = r_lo + qr;                  // in-bounds for k<KBAND
            const int i0 = qrow - ce0, i1 = qc - ce1;
            float coef = 0.f;
            if (i0 >= -2 && i0 <= 2 && i1 >= -2 && i1 <= 2 && k < KBAND) {
                const float d0 = (float)qrow - p0, d1 = (float)qc - p1;
                coef = sw * __expf(-0.5f * (d0 * d0 + d1 * d1));
            }
            af[Kt][j] = (_Float16)coef;
        }
    }

    // ---- zero the K-pad once (LDS garbage * af=0 would still make NaN) ----
    // pad ks 392..423 for all 64 batches: 64*8 groups of 4 halfs
    for (int s = tid; s < NB * 8; s += BLOCK) {
        const int b = s >> 3, kg = s & 7;
        *(half4h*)&X16[b * XPITCH + KBAND + kg * 4] = (half4h){0, 0, 0, 0};
    }

    const int tile0 = chunk * tilesPerChunk;
    for (int t = 0; t < tilesPerChunk; ++t) {
        const int tile = tile0 + t;
        if (tile >= totalTiles) break;
        const int bbase = tile * NB;

        __syncthreads();                                 // X16 free (prev compute + pad-init)
        // ---- stage: 64 batches x 392 f32 -> f16, unconditional coalesced float4 loads ----
        {
            const float* src0 = x + (size_t)bbase * NPIX + r_lo * 28;  // 16B-aligned (112*r_lo)
#pragma unroll
            for (int i = 0; i < 14; ++i) {               // 6272 tasks / 448 = 14, independent (MLP)
                const int s = tid + i * BLOCK;
                const int b = s / 98, kg = s - 98 * b;   // 98 float4-groups cover 392 ks
                const float4 v = *(const float4*)(src0 + (size_t)b * NPIX + kg * 4);
                half4h h = { (_Float16)v.x, (_Float16)v.y, (_Float16)v.z, (_Float16)v.w };
                *(half4h*)&X16[b * XPITCH + kg * 4] = h; // 8B write, conflict-free
            }
        }
        __syncthreads();

        // ---- MFMA: D[112 x 64] += A[112 x 416] * X^T, A from registers ----
        floatx4 acc[NNT];
#pragma unroll
        for (int Nt = 0; Nt < NNT; ++Nt) acc[Nt] = (floatx4){0.f, 0.f, 0.f, 0.f};
#pragma unroll
        for (int Kt = 0; Kt < NKT; ++Kt) {
#pragma unroll
            for (int Nt = 0; Nt < NNT; ++Nt) {
                const half8 bf = *(const half8*)&X16[(Nt * 16 + ml) * XPITCH + Kt * 32 + g * 8];
                acc[Nt] = __builtin_amdgcn_mfma_f32_16x16x32_f16(af[Kt], bf, acc[Nt], 0, 0, 0);
            }
        }

        // ---- store: lane(g,ml) holds batch ml, pixels g*4..+3 -> full 64B lines per batch ----
        const int pg = strip * M_PIX + w * 16 + g * 4;
#pragma unroll
        for (int Nt = 0; Nt < NNT; ++Nt) {
            const int bg = bbase + Nt * 16 + ml;
            *(floatx4*)&out[(size_t)bg * NPIX + pg] = acc[Nt];
        }
    }
}

extern "C" void kernel_launch(void* const* d_in, const int* in_sizes, int n_in,
                              void* d_out, int out_size, void* d_ws, size_t ws_size,
                              hipStream_t stream) {
    const float* x      = (const float*)d_in[0];   // (32768,1,28,28) fp32
    const float* pos2d  = (const float*)d_in[1];   // (28,28,2) fp32
    const float* weight = (const float*)d_in[2];   // (28,28) fp32
    float* out = (float*)d_out;

    const int B = in_sizes[0] / NPIX;              // 32768
    const int totalTiles = B / NB;                 // 512 batch-tiles per strip
    const int tilesPerChunk = (totalTiles + CHUNKS - 1) / CHUNKS;   // 7

    // strip fastest in grid: all 7 strips of a batch-chunk co-resident -> band
    // overlap re-reads served by LLC (FETCH stayed ~1.4x in R4 with this order)
    hipLaunchKernelGGL(axs_89807766159734_kernel, dim3(NSTRIP, CHUNKS), dim3(BLOCK), 0, stream,
                       x, pos2d, weight, out, tilesPerChunk, totalTiles);
}